// Round 1
// baseline (1780.674 us; speedup 1.0000x reference)
//
#include <hip/hip_runtime.h>
#include <math.h>

#define N_NODES 50000
#define N_EDGES 800000
#define BATCH   4
#define C1      64
#define C2      32
#define BN      (BATCH * N_NODES)

// ---------- kernels ----------

__global__ void k_deg_init(float* __restrict__ deg) {
    int n = blockIdx.x * 256 + threadIdx.x;
    if (n < N_NODES) deg[n] = 1.0f;   // self-loop
}

__global__ void k_edge_prep(const int* __restrict__ ei,
                            int* __restrict__ src32, int* __restrict__ dst32,
                            float* __restrict__ deg) {
    int e = blockIdx.x * 256 + threadIdx.x;
    if (e >= N_EDGES) return;
    int s = ei[e];
    int d = ei[N_EDGES + e];
    src32[e] = s;
    dst32[e] = d;
    atomicAdd(&deg[d], 1.0f);
}

// deg -> dinv in place; also layer-1 pre-propagation: y1 = dinv * x, z1 = y1 (self-loop)
__global__ void k_dinv_l1pre(float* __restrict__ dinv,
                             const float* __restrict__ x,
                             float* __restrict__ y1, float* __restrict__ z1) {
    int n = blockIdx.x * 256 + threadIdx.x;
    if (n >= N_NODES) return;
    float di = rsqrtf(dinv[n]);   // deg >= 1 always
    dinv[n] = di;
#pragma unroll
    for (int b = 0; b < BATCH; b++) {
        float v = x[b * N_NODES + n] * di;
        y1[b * N_NODES + n] = v;
        z1[b * N_NODES + n] = v;
    }
}

// 1-channel edge scatter (layers 1 and 3): z[b,dst] += y[b,src]
__global__ void k_scat1(const int* __restrict__ src32, const int* __restrict__ dst32,
                        const float* __restrict__ y, float* __restrict__ z) {
    int tid = blockIdx.x * 256 + threadIdx.x;
    if (tid >= BATCH * N_EDGES) return;
    int b = tid / N_EDGES;
    int e = tid - b * N_EDGES;
    atomicAdd(&z[b * N_NODES + dst32[e]], y[b * N_NODES + src32[e]]);
}

// fused: px = dinv*z1; h1 = relu(px*W1+b1); t2 = h1@W2; y2 = dinv*t2; z2 = y2
__global__ __launch_bounds__(256) void k_l2(
        const float* __restrict__ dinv, const float* __restrict__ z1,
        const float* __restrict__ W1, const float* __restrict__ b1,
        const float* __restrict__ W2,
        float* __restrict__ y2, float* __restrict__ z2) {
    __shared__ float sW1[C1], sb1[C1], sW2[C1 * C2];
    int lt = threadIdx.x;
    for (int i = lt; i < C1; i += 256) { sW1[i] = W1[i]; sb1[i] = b1[i]; }
    for (int i = lt; i < C1 * C2; i += 256) sW2[i] = W2[i];
    __syncthreads();

    int t = blockIdx.x * 256 + lt;
    if (t >= BN) return;
    int n = t % N_NODES;          // t = b*N + n
    float di = dinv[n];
    float px = di * z1[t];

    float acc[C2];
#pragma unroll
    for (int j = 0; j < C2; j++) acc[j] = 0.0f;

    for (int c = 0; c < C1; c++) {
        float h = fmaxf(px * sW1[c] + sb1[c], 0.0f);
        const float4* row = (const float4*)&sW2[c * C2];
#pragma unroll
        for (int j4 = 0; j4 < C2 / 4; j4++) {
            float4 w = row[j4];
            acc[4 * j4 + 0] += h * w.x;
            acc[4 * j4 + 1] += h * w.y;
            acc[4 * j4 + 2] += h * w.z;
            acc[4 * j4 + 3] += h * w.w;
        }
    }

    float4* yo = (float4*)&y2[(size_t)t * C2];
    float4* zo = (float4*)&z2[(size_t)t * C2];
#pragma unroll
    for (int j4 = 0; j4 < C2 / 4; j4++) {
        float4 v;
        v.x = acc[4 * j4 + 0] * di;
        v.y = acc[4 * j4 + 1] * di;
        v.z = acc[4 * j4 + 2] * di;
        v.w = acc[4 * j4 + 3] * di;
        yo[j4] = v;
        zo[j4] = v;
    }
}

// 32-channel edge scatter: thread per (b, e, j4-chunk-of-4)
__global__ void k_scat2(const int* __restrict__ src32, const int* __restrict__ dst32,
                        const float* __restrict__ y2, float* __restrict__ z2) {
    int tid = blockIdx.x * 256 + threadIdx.x;
    if (tid >= BATCH * N_EDGES * 8) return;
    int jv = tid & 7;
    int r  = tid >> 3;
    int b  = r / N_EDGES;
    int e  = r - b * N_EDGES;
    int s = src32[e];
    int d = dst32[e];
    float4 v = ((const float4*)y2)[(size_t)(b * N_NODES + s) * 8 + jv];
    float* zp = &z2[(size_t)(b * N_NODES + d) * C2 + jv * 4];
    atomicAdd(zp + 0, v.x);
    atomicAdd(zp + 1, v.y);
    atomicAdd(zp + 2, v.z);
    atomicAdd(zp + 3, v.w);
}

// layer-2 epilogue + layer-3 transform + layer-3 pre-propagation
__global__ void k_l3(const float* __restrict__ dinv, const float* __restrict__ z2,
                     const float* __restrict__ b2, const float* __restrict__ W3,
                     float* __restrict__ y3, float* __restrict__ z3) {
    int t = blockIdx.x * 256 + threadIdx.x;
    if (t >= BN) return;
    int n = t % N_NODES;
    float di = dinv[n];
    float acc = 0.0f;
#pragma unroll
    for (int j = 0; j < C2; j++) {
        float o = fmaxf(di * z2[(size_t)t * C2 + j] + b2[j], 0.0f);
        acc += o * W3[j];
    }
    float v = acc * di;   // y3 = dinv * h3
    y3[t] = v;
    z3[t] = v;
}

__global__ void k_out(const float* __restrict__ dinv, const float* __restrict__ z3,
                      const float* __restrict__ b3, float* __restrict__ out) {
    int t = blockIdx.x * 256 + threadIdx.x;
    if (t >= BN) return;
    int n = t % N_NODES;
    float v = dinv[n] * z3[t] + b3[0];
    out[t] = 1.0f / (1.0f + expf(-v));
}

// ---------- launch ----------

extern "C" void kernel_launch(void* const* d_in, const int* in_sizes, int n_in,
                              void* d_out, int out_size, void* d_ws, size_t ws_size,
                              hipStream_t stream) {
    const float* x   = (const float*)d_in[0];
    const int*   ei  = (const int*)d_in[1];   // edge_index as int32 per harness convention
    const float* W1  = (const float*)d_in[2];
    const float* b1  = (const float*)d_in[3];
    const float* W2  = (const float*)d_in[4];
    const float* b2  = (const float*)d_in[5];
    const float* W3  = (const float*)d_in[6];
    const float* b3  = (const float*)d_in[7];
    float* out = (float*)d_out;

    // workspace carve-up (256B aligned)
    char* ws = (char*)d_ws;
    size_t off = 0;
    auto carve = [&](size_t bytes) {
        void* p = ws + off;
        off = (off + bytes + 255) & ~(size_t)255;
        return p;
    };
    float* dinv  = (float*)carve(N_NODES * 4);
    int*   src32 = (int*)  carve(N_EDGES * 4);
    int*   dst32 = (int*)  carve(N_EDGES * 4);
    float* y1    = (float*)carve(BN * 4);
    float* z1    = (float*)carve(BN * 4);
    float* y2    = (float*)carve((size_t)BN * C2 * 4);
    float* z2    = (float*)carve((size_t)BN * C2 * 4);
    float* y3    = (float*)carve(BN * 4);
    float* z3    = (float*)carve(BN * 4);

    dim3 blk(256);

    k_deg_init  <<<(N_NODES + 255) / 256, blk, 0, stream>>>(dinv);
    k_edge_prep <<<(N_EDGES + 255) / 256, blk, 0, stream>>>(ei, src32, dst32, dinv);
    k_dinv_l1pre<<<(N_NODES + 255) / 256, blk, 0, stream>>>(dinv, x, y1, z1);
    k_scat1     <<<(BATCH * N_EDGES + 255) / 256, blk, 0, stream>>>(src32, dst32, y1, z1);
    k_l2        <<<(BN + 255) / 256, blk, 0, stream>>>(dinv, z1, W1, b1, W2, y2, z2);
    k_scat2     <<<(BATCH * N_EDGES * 8 + 255) / 256, blk, 0, stream>>>(src32, dst32, y2, z2);
    k_l3        <<<(BN + 255) / 256, blk, 0, stream>>>(dinv, z2, b2, W3, y3, z3);
    k_scat1     <<<(BATCH * N_EDGES + 255) / 256, blk, 0, stream>>>(src32, dst32, y3, z3);
    k_out       <<<(BN + 255) / 256, blk, 0, stream>>>(dinv, z3, b3, out);
}

// Round 2
// 362.203 us; speedup vs baseline: 4.9162x; 4.9162x over previous
//
#include <hip/hip_runtime.h>
#include <math.h>

#define N_NODES 50000
#define N_EDGES 800000
#define BATCH   4
#define C1      64
#define C2      32
#define BN      (BATCH * N_NODES)

// ---------------- CSR build ----------------

__global__ void k_zero(int* __restrict__ cnt) {
    int n = blockIdx.x * 256 + threadIdx.x;
    if (n < N_NODES) cnt[n] = 0;
}

// histogram of in-degree (dst)
__global__ void k_hist(const int* __restrict__ ei, int* __restrict__ cnt) {
    int e = blockIdx.x * 256 + threadIdx.x;
    if (e >= N_EDGES) return;
    atomicAdd(&cnt[ei[N_EDGES + e]], 1);
}

// single-block exclusive scan over cnt -> row/cursor; dinv = rsqrt(deg+1)
__global__ __launch_bounds__(1024) void k_scan(const int* __restrict__ cnt,
                                               int* __restrict__ row,
                                               int* __restrict__ cursor,
                                               float* __restrict__ dinv) {
    __shared__ int buf[1024];
    int tid = threadIdx.x;
    int offset = 0;
    const int CH = (N_NODES + 1023) / 1024;
    for (int c = 0; c < CH; c++) {
        int i = c * 1024 + tid;
        int v = (i < N_NODES) ? cnt[i] : 0;
        buf[tid] = v;
        __syncthreads();
        int x = v;
        for (int s = 1; s < 1024; s <<= 1) {
            int y = (tid >= s) ? buf[tid - s] : 0;
            __syncthreads();
            x += y;
            buf[tid] = x;
            __syncthreads();
        }
        int excl = x - v;
        if (i < N_NODES) {
            row[i] = offset + excl;
            cursor[i] = offset + excl;
            dinv[i] = rsqrtf((float)(v + 1));  // +1 self-loop
        }
        int tot = buf[1023];
        __syncthreads();
        offset += tot;
    }
    if (tid == 0) row[N_NODES] = offset;
}

__global__ void k_fill(const int* __restrict__ ei, int* __restrict__ cursor,
                       int* __restrict__ csr) {
    int e = blockIdx.x * 256 + threadIdx.x;
    if (e >= N_EDGES) return;
    int s = ei[e];
    int d = ei[N_EDGES + e];
    int pos = atomicAdd(&cursor[d], 1);
    csr[pos] = s;
}

// ---------------- compute ----------------

// xd[b,n] = x[b,n] * dinv[n]
__global__ void k_xd(const float* __restrict__ x, const float* __restrict__ dinv,
                     float* __restrict__ xd) {
    int t = blockIdx.x * 256 + threadIdx.x;
    if (t >= BN) return;
    xd[t] = x[t] * dinv[t % N_NODES];
}

// fused layer1 aggregation + dense 1->64 (relu) -> 64x32 matvec; y2 = dinv * (h1@W2)
__global__ __launch_bounds__(256) void k_l1l2(
        const float* __restrict__ dinv, const float* __restrict__ xd,
        const int* __restrict__ row, const int* __restrict__ csr,
        const float* __restrict__ W1, const float* __restrict__ b1,
        const float* __restrict__ W2,
        float* __restrict__ y2) {
    __shared__ float sW1[C1], sb1[C1], sW2[C1 * C2];
    int lt = threadIdx.x;
    for (int i = lt; i < C1; i += 256) { sW1[i] = W1[i]; sb1[i] = b1[i]; }
    for (int i = lt; i < C1 * C2; i += 256) sW2[i] = W2[i];
    __syncthreads();

    int t = blockIdx.x * 256 + lt;
    if (t >= BN) return;
    int n = t % N_NODES;
    int base = t - n;                 // b*N
    float di = dinv[n];

    float s = xd[t];                  // self-loop
    int r0 = row[n], r1 = row[n + 1];
    int k = r0;
    for (; k + 1 < r1; k += 2) {
        int s0 = csr[k], s1 = csr[k + 1];
        s += xd[base + s0] + xd[base + s1];
    }
    if (k < r1) s += xd[base + csr[k]];
    float px = di * s;

    float acc[C2];
#pragma unroll
    for (int j = 0; j < C2; j++) acc[j] = 0.0f;

    for (int c = 0; c < C1; c++) {
        float h = fmaxf(px * sW1[c] + sb1[c], 0.0f);
        const float4* rw = (const float4*)&sW2[c * C2];
#pragma unroll
        for (int j4 = 0; j4 < C2 / 4; j4++) {
            float4 w = rw[j4];
            acc[4 * j4 + 0] += h * w.x;
            acc[4 * j4 + 1] += h * w.y;
            acc[4 * j4 + 2] += h * w.z;
            acc[4 * j4 + 3] += h * w.w;
        }
    }

    float4* yo = (float4*)&y2[(size_t)t * C2];
#pragma unroll
    for (int j4 = 0; j4 < C2 / 4; j4++) {
        float4 v;
        v.x = acc[4 * j4 + 0] * di;
        v.y = acc[4 * j4 + 1] * di;
        v.z = acc[4 * j4 + 2] * di;
        v.w = acc[4 * j4 + 3] * di;
        yo[j4] = v;
    }
}

// layer-2 aggregation: z2[b,n,:] = y2[b,n,:] + sum_{s in in(n)} y2[b,s,:]
// thread = (b, n, quad); 8 consecutive threads share one (b,n) -> coalesced 128B per edge
__global__ __launch_bounds__(256) void k_agg2(
        const float* __restrict__ y2, const int* __restrict__ row,
        const int* __restrict__ csr, float* __restrict__ z2) {
    int tid = blockIdx.x * 256 + threadIdx.x;
    if (tid >= BN * 8) return;
    int j4  = tid & 7;
    int idx = tid >> 3;               // b*N + n
    int n = idx % N_NODES;
    int base = idx - n;               // b*N
    const float4* Y = (const float4*)y2;

    float4 a = Y[(size_t)idx * 8 + j4];   // self
    int r0 = row[n], r1 = row[n + 1];
    int k = r0;
    for (; k + 1 < r1; k += 2) {
        int s0 = csr[k], s1 = csr[k + 1];
        float4 v0 = Y[(size_t)(base + s0) * 8 + j4];
        float4 v1 = Y[(size_t)(base + s1) * 8 + j4];
        a.x += v0.x + v1.x; a.y += v0.y + v1.y;
        a.z += v0.z + v1.z; a.w += v0.w + v1.w;
    }
    if (k < r1) {
        float4 v = Y[(size_t)(base + csr[k]) * 8 + j4];
        a.x += v.x; a.y += v.y; a.z += v.z; a.w += v.w;
    }
    ((float4*)z2)[(size_t)idx * 8 + j4] = a;
}

// layer-2 epilogue (relu(dinv*z2+b2)) + layer-3 transform: y3 = dinv*(h2@W3)
__global__ void k_l3(const float* __restrict__ dinv, const float* __restrict__ z2,
                     const float* __restrict__ b2, const float* __restrict__ W3,
                     float* __restrict__ y3) {
    int t = blockIdx.x * 256 + threadIdx.x;
    if (t >= BN) return;
    int n = t % N_NODES;
    float di = dinv[n];
    float acc = 0.0f;
#pragma unroll
    for (int j = 0; j < C2; j++) {
        float o = fmaxf(di * z2[(size_t)t * C2 + j] + b2[j], 0.0f);
        acc += o * W3[j];
    }
    y3[t] = acc * di;
}

// layer-3 aggregation + sigmoid output
__global__ void k_agg3out(const float* __restrict__ dinv, const float* __restrict__ y3,
                          const int* __restrict__ row, const int* __restrict__ csr,
                          const float* __restrict__ b3, float* __restrict__ out) {
    int t = blockIdx.x * 256 + threadIdx.x;
    if (t >= BN) return;
    int n = t % N_NODES;
    int base = t - n;
    float a = y3[t];                  // self
    int r0 = row[n], r1 = row[n + 1];
    int k = r0;
    for (; k + 1 < r1; k += 2) {
        int s0 = csr[k], s1 = csr[k + 1];
        a += y3[base + s0] + y3[base + s1];
    }
    if (k < r1) a += y3[base + csr[k]];
    float v = dinv[n] * a + b3[0];
    out[t] = 1.0f / (1.0f + expf(-v));
}

// ---------------- launch ----------------

extern "C" void kernel_launch(void* const* d_in, const int* in_sizes, int n_in,
                              void* d_out, int out_size, void* d_ws, size_t ws_size,
                              hipStream_t stream) {
    const float* x   = (const float*)d_in[0];
    const int*   ei  = (const int*)d_in[1];
    const float* W1  = (const float*)d_in[2];
    const float* b1  = (const float*)d_in[3];
    const float* W2  = (const float*)d_in[4];
    const float* b2  = (const float*)d_in[5];
    const float* W3  = (const float*)d_in[6];
    const float* b3  = (const float*)d_in[7];
    float* out = (float*)d_out;

    char* ws = (char*)d_ws;
    size_t off = 0;
    auto carve = [&](size_t bytes) {
        void* p = ws + off;
        off = (off + bytes + 255) & ~(size_t)255;
        return p;
    };
    int*   cnt    = (int*)  carve(N_NODES * 4);
    int*   row    = (int*)  carve((N_NODES + 1) * 4);
    int*   cursor = (int*)  carve(N_NODES * 4);
    float* dinv   = (float*)carve(N_NODES * 4);
    int*   csr    = (int*)  carve(N_EDGES * 4);
    float* xd     = (float*)carve(BN * 4);
    float* y2     = (float*)carve((size_t)BN * C2 * 4);
    float* z2     = (float*)carve((size_t)BN * C2 * 4);
    float* y3     = (float*)carve(BN * 4);

    dim3 blk(256);

    k_zero    <<<(N_NODES + 255) / 256, blk, 0, stream>>>(cnt);
    k_hist    <<<(N_EDGES + 255) / 256, blk, 0, stream>>>(ei, cnt);
    k_scan    <<<1, 1024, 0, stream>>>(cnt, row, cursor, dinv);
    k_fill    <<<(N_EDGES + 255) / 256, blk, 0, stream>>>(ei, cursor, csr);
    k_xd      <<<(BN + 255) / 256, blk, 0, stream>>>(x, dinv, xd);
    k_l1l2    <<<(BN + 255) / 256, blk, 0, stream>>>(dinv, xd, row, csr, W1, b1, W2, y2);
    k_agg2    <<<(BN * 8 + 255) / 256, blk, 0, stream>>>(y2, row, csr, z2);
    k_l3      <<<(BN + 255) / 256, blk, 0, stream>>>(dinv, z2, b2, W3, y3);
    k_agg3out <<<(BN + 255) / 256, blk, 0, stream>>>(dinv, y3, row, csr, b3, out);
}

// Round 3
// 292.831 us; speedup vs baseline: 6.0809x; 1.2369x over previous
//
#include <hip/hip_runtime.h>
#include <math.h>

#define N_NODES 50000
#define N_EDGES 800000
#define BATCH   4
#define C1      64
#define C2      32
#define BN      (BATCH * N_NODES)

// ---------------- CSR build ----------------

__global__ void k_zero(int* __restrict__ cnt, int* __restrict__ gcount) {
    int n = blockIdx.x * 256 + threadIdx.x;
    if (n < N_NODES) cnt[n] = 0;
    if (n == 0) *gcount = 0;
}

// histogram of in-degree (dst)
__global__ void k_hist(const int* __restrict__ ei, int* __restrict__ cnt) {
    int e = blockIdx.x * 256 + threadIdx.x;
    if (e >= N_EDGES) return;
    atomicAdd(&cnt[ei[N_EDGES + e]], 1);
}

// wave-aggregated bump allocation of CSR row segments (order-free, no scan)
__global__ __launch_bounds__(256) void k_alloc(const int* __restrict__ cnt,
                                               int* __restrict__ row,
                                               int* __restrict__ cursor,
                                               float* __restrict__ dinv,
                                               int* __restrict__ gcount) {
    int n = blockIdx.x * 256 + threadIdx.x;
    int v = (n < N_NODES) ? cnt[n] : 0;
    int lane = threadIdx.x & 63;
    // inclusive shuffle scan over the wave
    int x = v;
#pragma unroll
    for (int s = 1; s < 64; s <<= 1) {
        int y = __shfl_up(x, s, 64);
        if (lane >= s) x += y;
    }
    int wave_total = __shfl(x, 63, 64);
    int base = 0;
    if (lane == 63) base = atomicAdd(gcount, wave_total);
    base = __shfl(base, 63, 64);
    if (n < N_NODES) {
        int r = base + (x - v);       // exclusive offset within wave
        row[n] = r;
        cursor[n] = r;
        dinv[n] = rsqrtf((float)(v + 1));   // +1 self-loop
    }
}

__global__ void k_fill(const int* __restrict__ ei, int* __restrict__ cursor,
                       int* __restrict__ csr) {
    int e = blockIdx.x * 256 + threadIdx.x;
    if (e >= N_EDGES) return;
    int s = ei[e];
    int d = ei[N_EDGES + e];
    int pos = atomicAdd(&cursor[d], 1);
    csr[pos] = s;
}

// ---------------- compute ----------------

// xd[b,n] = x[b,n] * dinv[n]
__global__ void k_xd(const float* __restrict__ x, const float* __restrict__ dinv,
                     float* __restrict__ xd) {
    int t = blockIdx.x * 256 + threadIdx.x;
    if (t >= BN) return;
    xd[t] = x[t] * dinv[t % N_NODES];
}

// fused layer1 aggregation + dense 1->64 (relu) -> 64x32 matvec; y2 = dinv * (h1@W2)
__global__ __launch_bounds__(256) void k_l1l2(
        const float* __restrict__ dinv, const float* __restrict__ xd,
        const int* __restrict__ row, const int* __restrict__ cnt,
        const int* __restrict__ csr,
        const float* __restrict__ W1, const float* __restrict__ b1,
        const float* __restrict__ W2,
        float* __restrict__ y2) {
    __shared__ float sW1[C1], sb1[C1], sW2[C1 * C2];
    int lt = threadIdx.x;
    for (int i = lt; i < C1; i += 256) { sW1[i] = W1[i]; sb1[i] = b1[i]; }
    for (int i = lt; i < C1 * C2; i += 256) sW2[i] = W2[i];
    __syncthreads();

    int t = blockIdx.x * 256 + lt;
    if (t >= BN) return;
    int n = t % N_NODES;
    int base = t - n;                 // b*N
    float di = dinv[n];

    float s = xd[t];                  // self-loop
    int r0 = row[n], r1 = r0 + cnt[n];
    int k = r0;
    for (; k + 1 < r1; k += 2) {
        int s0 = csr[k], s1 = csr[k + 1];
        s += xd[base + s0] + xd[base + s1];
    }
    if (k < r1) s += xd[base + csr[k]];
    float px = di * s;

    float acc[C2];
#pragma unroll
    for (int j = 0; j < C2; j++) acc[j] = 0.0f;

    for (int c = 0; c < C1; c++) {
        float h = fmaxf(px * sW1[c] + sb1[c], 0.0f);
        const float4* rw = (const float4*)&sW2[c * C2];
#pragma unroll
        for (int j4 = 0; j4 < C2 / 4; j4++) {
            float4 w = rw[j4];
            acc[4 * j4 + 0] += h * w.x;
            acc[4 * j4 + 1] += h * w.y;
            acc[4 * j4 + 2] += h * w.z;
            acc[4 * j4 + 3] += h * w.w;
        }
    }

    float4* yo = (float4*)&y2[(size_t)t * C2];
#pragma unroll
    for (int j4 = 0; j4 < C2 / 4; j4++) {
        float4 v;
        v.x = acc[4 * j4 + 0] * di;
        v.y = acc[4 * j4 + 1] * di;
        v.z = acc[4 * j4 + 2] * di;
        v.w = acc[4 * j4 + 3] * di;
        yo[j4] = v;
    }
}

// layer-2 aggregation: z2[b,n,:] = y2[b,n,:] + sum_{s in in(n)} y2[b,s,:]
// thread = (b, n, quad); 8 consecutive threads share one (b,n) -> coalesced 128B per edge
__global__ __launch_bounds__(256) void k_agg2(
        const float* __restrict__ y2, const int* __restrict__ row,
        const int* __restrict__ cnt, const int* __restrict__ csr,
        float* __restrict__ z2) {
    int tid = blockIdx.x * 256 + threadIdx.x;
    if (tid >= BN * 8) return;
    int j4  = tid & 7;
    int idx = tid >> 3;               // b*N + n
    int n = idx % N_NODES;
    int base = idx - n;               // b*N
    const float4* Y = (const float4*)y2;

    float4 a = Y[(size_t)idx * 8 + j4];   // self
    int r0 = row[n], r1 = r0 + cnt[n];
    int k = r0;
    for (; k + 1 < r1; k += 2) {
        int s0 = csr[k], s1 = csr[k + 1];
        float4 v0 = Y[(size_t)(base + s0) * 8 + j4];
        float4 v1 = Y[(size_t)(base + s1) * 8 + j4];
        a.x += v0.x + v1.x; a.y += v0.y + v1.y;
        a.z += v0.z + v1.z; a.w += v0.w + v1.w;
    }
    if (k < r1) {
        float4 v = Y[(size_t)(base + csr[k]) * 8 + j4];
        a.x += v.x; a.y += v.y; a.z += v.z; a.w += v.w;
    }
    ((float4*)z2)[(size_t)idx * 8 + j4] = a;
}

// layer-2 epilogue (relu(dinv*z2+b2)) + layer-3 transform: y3 = dinv*(h2@W3)
__global__ void k_l3(const float* __restrict__ dinv, const float* __restrict__ z2,
                     const float* __restrict__ b2, const float* __restrict__ W3,
                     float* __restrict__ y3) {
    int t = blockIdx.x * 256 + threadIdx.x;
    if (t >= BN) return;
    int n = t % N_NODES;
    float di = dinv[n];
    const float4* Z = (const float4*)&z2[(size_t)t * C2];
    float acc = 0.0f;
#pragma unroll
    for (int j4 = 0; j4 < C2 / 4; j4++) {
        float4 z = Z[j4];
        acc += fmaxf(di * z.x + b2[4 * j4 + 0], 0.0f) * W3[4 * j4 + 0];
        acc += fmaxf(di * z.y + b2[4 * j4 + 1], 0.0f) * W3[4 * j4 + 1];
        acc += fmaxf(di * z.z + b2[4 * j4 + 2], 0.0f) * W3[4 * j4 + 2];
        acc += fmaxf(di * z.w + b2[4 * j4 + 3], 0.0f) * W3[4 * j4 + 3];
    }
    y3[t] = acc * di;
}

// layer-3 aggregation + sigmoid output
__global__ void k_agg3out(const float* __restrict__ dinv, const float* __restrict__ y3,
                          const int* __restrict__ row, const int* __restrict__ cnt,
                          const int* __restrict__ csr,
                          const float* __restrict__ b3, float* __restrict__ out) {
    int t = blockIdx.x * 256 + threadIdx.x;
    if (t >= BN) return;
    int n = t % N_NODES;
    int base = t - n;
    float a = y3[t];                  // self
    int r0 = row[n], r1 = r0 + cnt[n];
    int k = r0;
    for (; k + 1 < r1; k += 2) {
        int s0 = csr[k], s1 = csr[k + 1];
        a += y3[base + s0] + y3[base + s1];
    }
    if (k < r1) a += y3[base + csr[k]];
    float v = dinv[n] * a + b3[0];
    out[t] = 1.0f / (1.0f + expf(-v));
}

// ---------------- launch ----------------

extern "C" void kernel_launch(void* const* d_in, const int* in_sizes, int n_in,
                              void* d_out, int out_size, void* d_ws, size_t ws_size,
                              hipStream_t stream) {
    const float* x   = (const float*)d_in[0];
    const int*   ei  = (const int*)d_in[1];
    const float* W1  = (const float*)d_in[2];
    const float* b1  = (const float*)d_in[3];
    const float* W2  = (const float*)d_in[4];
    const float* b2  = (const float*)d_in[5];
    const float* W3  = (const float*)d_in[6];
    const float* b3  = (const float*)d_in[7];
    float* out = (float*)d_out;

    char* ws = (char*)d_ws;
    size_t off = 0;
    auto carve = [&](size_t bytes) {
        void* p = ws + off;
        off = (off + bytes + 255) & ~(size_t)255;
        return p;
    };
    int*   cnt    = (int*)  carve(N_NODES * 4);
    int*   row    = (int*)  carve(N_NODES * 4);
    int*   cursor = (int*)  carve(N_NODES * 4);
    float* dinv   = (float*)carve(N_NODES * 4);
    int*   csr    = (int*)  carve(N_EDGES * 4);
    float* xd     = (float*)carve(BN * 4);
    float* y2     = (float*)carve((size_t)BN * C2 * 4);
    float* z2     = (float*)carve((size_t)BN * C2 * 4);
    float* y3     = (float*)carve(BN * 4);
    int*   gcount = (int*)  carve(4);

    dim3 blk(256);

    k_zero    <<<(N_NODES + 255) / 256, blk, 0, stream>>>(cnt, gcount);
    k_hist    <<<(N_EDGES + 255) / 256, blk, 0, stream>>>(ei, cnt);
    k_alloc   <<<(N_NODES + 255) / 256, blk, 0, stream>>>(cnt, row, cursor, dinv, gcount);
    k_fill    <<<(N_EDGES + 255) / 256, blk, 0, stream>>>(ei, cursor, csr);
    k_xd      <<<(BN + 255) / 256, blk, 0, stream>>>(x, dinv, xd);
    k_l1l2    <<<(BN + 255) / 256, blk, 0, stream>>>(dinv, xd, row, cnt, csr, W1, b1, W2, y2);
    k_agg2    <<<(BN * 8 + 255) / 256, blk, 0, stream>>>(y2, row, cnt, csr, z2);
    k_l3      <<<(BN + 255) / 256, blk, 0, stream>>>(dinv, z2, b2, W3, y3);
    k_agg3out <<<(BN + 255) / 256, blk, 0, stream>>>(dinv, y3, row, cnt, csr, b3, out);
}